// Round 9
// baseline (828.711 us; speedup 1.0000x reference)
//
#include <hip/hip_runtime.h>
#include <hip/hip_fp16.h>
#include <math.h>

#define N_NODES 50000
#define N_REL   1000
#define D       128
#define NNZ     800000

#define RB    512                  // rows per k1 bin (full-line write runs)
#define NBIN  98                   // ceil(50000/512)
#define CAP   10240                // slots/bin: mean 8184, sigma ~90
#define CH    2048                 // edges per partition chunk
#define NCH   ((NNZ + CH - 1) / CH)   // 391 chunks/blocks
#define K1T   512
#define K1E   (CH / K1T)           // 4 edges/thread

// ===== K1: scores + f32->f16 convert + LDS-sorted bin partition + rel histogram =====
// Edge pack (u64): col:16 | rel:10 | rowlocal:9. 98 bins -> ~21-edge (168B) runs.
__global__ void __launch_bounds__(K1T)
k1_kernel(const int* __restrict__ rows, const int* __restrict__ cols,
          const int* __restrict__ rel, const float* __restrict__ dual,
          const float* __restrict__ conv_w, const float* __restrict__ conv_b,
          const float* __restrict__ inlayer, float* __restrict__ exp_scores,
          unsigned* __restrict__ relcnt, unsigned* __restrict__ bincur,
          unsigned long long* __restrict__ binbuf, __half2* __restrict__ hinl) {
    __shared__ unsigned long long sbuf[CH];     // 16 KB chunk staging (bin-sorted)
    __shared__ unsigned char sbin[CH];          // 2 KB per-slot bin id (98 < 256)
    __shared__ unsigned lcnt[NBIN], lstart[NBIN], lgb[NBIN];
    __shared__ unsigned lrel[N_REL];            // 4 KB relation histogram
    __shared__ unsigned w0sum;
    int t = threadIdx.x;
    int gtid = blockIdx.x * K1T + t;
    int lane = t & 63;

    // --- relation scores: one wave per relation (first 1000 waves of the grid) ---
    int wid = gtid >> 6;
    if (wid < N_REL) {
        const float* row = dual + (long)wid * D;
        float s = row[lane] * conv_w[lane] + row[lane + 64] * conv_w[lane + 64];
        #pragma unroll
        for (int off = 32; off > 0; off >>= 1) s += __shfl_down(s, off);
        if (lane == 0) {
            float v = s + conv_b[0];
            v = (v >= 0.f) ? v : 0.01f * v;        // leaky_relu
            exp_scores[wid] = expf(v);             // scores ~N(0,1): safe
        }
    }

    // --- f32 -> f16 convert (grid-stride float4, coalesced) ---
    const float4* src4 = (const float4*)inlayer;
    uint2* dst2 = (uint2*)hinl;
    for (int i = gtid; i < N_NODES * D / 4; i += NCH * K1T) {
        float4 f = src4[i];
        __half2 h0 = __floats2half2_rn(f.x, f.y);
        __half2 h1 = __floats2half2_rn(f.z, f.w);
        uint2 o; o.x = *(unsigned*)&h0; o.y = *(unsigned*)&h1;
        dst2[i] = o;
    }

    // --- partition this block's 2048-edge chunk ---
    if (t < NBIN) lcnt[t] = 0;
    for (int i = t; i < N_REL; i += K1T) lrel[i] = 0;
    __syncthreads();

    int n = NNZ - blockIdx.x * CH; if (n > CH) n = CH;   // tail = 1280 (mult of 4)
    int base4 = blockIdx.x * (CH / 4);

    int       ebin[K1E];
    unsigned  erank[K1E];
    unsigned long long epack[K1E];
    bool has = (4 * t < n);
    int4 rr, cc, qq;
    if (has) {
        rr = ((const int4*)rows)[base4 + t];
        cc = ((const int4*)cols)[base4 + t];
        qq = ((const int4*)rel)[base4 + t];
    }
    #pragma unroll
    for (int k = 0; k < K1E; ++k) {
        if (has) {
            int r = (k == 0) ? rr.x : (k == 1) ? rr.y : (k == 2) ? rr.z : rr.w;
            int c = (k == 0) ? cc.x : (k == 1) ? cc.y : (k == 2) ? cc.z : cc.w;
            int q = (k == 0) ? qq.x : (k == 1) ? qq.y : (k == 2) ? qq.z : qq.w;
            int b = r >> 9;
            epack[k] = (unsigned long long)(unsigned)c
                     | ((unsigned long long)(unsigned)q << 16)
                     | ((unsigned long long)(unsigned)(r & 511) << 26);
            ebin[k] = b;
            erank[k] = atomicAdd(&lcnt[b], 1u);
            atomicAdd(&lrel[q], 1u);
        } else ebin[k] = -1;
    }
    __syncthreads();

    // exclusive scan of 98 bin counts (2 waves) + reserve global runs
    unsigned v = (t < NBIN) ? lcnt[t] : 0u;
    if (t < 128) {
        #pragma unroll
        for (int off = 1; off < 64; off <<= 1) {
            unsigned y = __shfl_up(v, off);
            if (lane >= off) v += y;
        }
        if (t == 63) w0sum = v;
    }
    __syncthreads();
    if (t >= 64 && t < 128) v += w0sum;
    if (t < NBIN) {
        lstart[t] = v - lcnt[t];
        lgb[t] = atomicAdd(&bincur[t * 16], lcnt[t]);   // padded cursors: 1/line
    }
    // flush relation histogram (lrel stable since previous barrier)
    for (int i = t; i < N_REL; i += K1T) {
        unsigned cv = lrel[i];
        if (cv) atomicAdd(&relcnt[i], cv);
    }
    __syncthreads();

    // LDS scatter into bin-sorted order
    #pragma unroll
    for (int k = 0; k < K1E; ++k) {
        if (ebin[k] >= 0) {
            unsigned p = lstart[ebin[k]] + erank[k];
            sbuf[p] = epack[k];
            sbin[p] = (unsigned char)ebin[k];
        }
    }
    __syncthreads();

    // coalesced run writes: ~21-edge (168B) runs -> mostly full 64B lines
    #pragma unroll
    for (int k = 0; k < K1E; ++k) {
        int j = k * K1T + t;
        if (j < n) {
            int b = sbin[j];
            unsigned slot = lgb[b] + (unsigned)j - lstart[b];
            if (slot < CAP)
                binbuf[(unsigned long long)b * CAP + slot] = sbuf[j];
        }
    }
}

// ===== K2: fused accumulate — block = (bin, quarter); shared 128-row LDS acc ======
// Waves stride disjoint 64-edge windows (w mod 8); each keeps edges of its
// block's quarter ((u>>7)==sub) -> every edge accumulated EXACTLY once.
// ds_add_f32 LDS atomics; SoA accA/accB -> 2 lanes/bank (conflict-free).
__global__ void __launch_bounds__(512)
acc_kernel(const unsigned* __restrict__ bincur,
           const unsigned long long* __restrict__ binbuf,
           const float* __restrict__ exp_scores,
           const unsigned* __restrict__ relcnt,
           const __half2* __restrict__ hinl, float* __restrict__ out) {
    __shared__ float accA[128 * 64];       // 32 KB: even dims, [row][lane]
    __shared__ float accB[128 * 64];       // 32 KB: odd dims
    int t = threadIdx.x, lane = t & 63, w = t >> 6;
    int b   = blockIdx.x >> 2;             // bin 0..97
    int sub = blockIdx.x & 3;              // row quarter within bin

    // zero accumulators (cooperative)
    for (int i = t; i < 128 * 64; i += 512) { accA[i] = 0.f; accB[i] = 0.f; }

    // per-wave denom (no extra barrier): denom = sum_r relcnt[r] * exp_scores[r]
    float dsum = 0.f;
    for (int i = lane; i < N_REL; i += 64)
        dsum += (float)relcnt[i] * exp_scores[i];
    #pragma unroll
    for (int off = 32; off > 0; off >>= 1) dsum += __shfl_down(dsum, off);
    float inv = 1.0f / __shfl(dsum, 0);

    __syncthreads();                       // acc zeroed before any ds_add

    unsigned nb = bincur[b * 16]; if (nb > CAP) nb = CAP;
    const unsigned long long* bb = binbuf + (unsigned long long)b * CAP;

    // scan bin: wave w takes windows == w (mod 8); ballot-filter quarter edges
    for (unsigned wi = (unsigned)w * 64u; wi < nb; wi += 512u) {
        unsigned e = wi + (unsigned)lane;
        unsigned lo = 0, u = 0; bool own = false;
        if (e < nb) {
            unsigned long long pk = bb[e];         // coalesced 512B/window, L2-hot
            lo = (unsigned)pk;                     // col:16 | rel:10 | rowlocal[5:0]
            u  = (unsigned)(pk >> 26) & 511u;      // full 9-bit rowlocal
            own = (u >> 7) == (unsigned)sub;
        }
        unsigned long long m = __ballot(own);
        while (m) {
            int i0 = __ffsll((long long)m) - 1; m &= m - 1;
            unsigned l0 = __shfl(lo, i0);
            unsigned u0 = __shfl(u, i0);           // rowlocal needs 7 bits: shfl u
            unsigned c  = l0 & 0xFFFFu;
            float    wv = exp_scores[(l0 >> 16) & 0x3FFu];   // uniform broadcast
            int      rl = (int)(u0 & 127u);        // row within quarter
            float2 f = __half22float2(hinl[(unsigned)c * 64u + (unsigned)lane]);
            atomicAdd(&accA[rl * 64 + lane], wv * f.x);      // ds_add_f32
            atomicAdd(&accB[rl * 64 + lane], wv * f.y);
        }
    }
    __syncthreads();

    // epilogue: write 128 rows x inv (wave w: rows w*16..w*16+15), coalesced 512B
    int node0 = b * RB + sub * 128;
    #pragma unroll
    for (int r = 0; r < 16; ++r) {
        int rl = w * 16 + r;
        int node = node0 + rl;
        if (node < N_NODES) {
            float2 o;
            o.x = accA[rl * 64 + lane] * inv;
            o.y = accB[rl * 64 + lane] * inv;
            ((float2*)out)[(long)node * 64 + lane] = o;
        }
    }
}

extern "C" void kernel_launch(void* const* d_in, const int* in_sizes, int n_in,
                              void* d_out, int out_size, void* d_ws, size_t ws_size,
                              hipStream_t stream) {
    const float* inlayer  = (const float*)d_in[0];
    const float* dual     = (const float*)d_in[1];
    const float* conv_w   = (const float*)d_in[2];
    const float* conv_b   = (const float*)d_in[3];
    const int*   edge_idx = (const int*)d_in[4];   // [2, NNZ]: rows then cols
    const int*   edge_rel = (const int*)d_in[5];
    float* out = (float*)d_out;
    const int* rows = edge_idx;
    const int* cols = edge_idx + NNZ;

    // workspace layout (16B aligned) — total ~20.9 MB
    char* ws = (char*)d_ws;
    float*              exp_scores = (float*)             (ws);             // 4 KB
    unsigned*           relcnt     = (unsigned*)          (ws + 4096);      // 4 KB (memset)
    unsigned*           bincur     = (unsigned*)          (ws + 8192);      // 98*64B (memset)
    unsigned long long* binbuf     = (unsigned long long*)(ws + 16384);     // 98*10240*8 = 8.03 MB
    __half2*            hinl       = (__half2*)           (ws + 16384 + 8028160); // 12.8 MB

    // zero relcnt + bincur in one 12 KB fill
    hipMemsetAsync(ws + 4096, 0, 12288, stream);

    k1_kernel<<<NCH, K1T, 0, stream>>>(rows, cols, edge_rel, dual, conv_w, conv_b,
                                       inlayer, exp_scores, relcnt, bincur,
                                       binbuf, hinl);
    acc_kernel<<<NBIN * 4, 512, 0, stream>>>(bincur, binbuf, exp_scores, relcnt,
                                             hinl, out);
}

// Round 10
// 147.531 us; speedup vs baseline: 5.6172x; 5.6172x over previous
//
#include <hip/hip_runtime.h>
#include <hip/hip_fp16.h>
#include <math.h>

#define N_NODES 50000
#define N_REL   1000
#define D       128
#define NNZ     800000

#define RB    512                  // rows per k1 bin (full-line write runs)
#define NBIN  98                   // ceil(50000/512)
#define CAP   10240                // slots/bin: mean 8184, sigma ~90
#define CH    2048                 // edges per partition chunk
#define NCH   ((NNZ + CH - 1) / CH)   // 391 chunks/blocks
#define K1T   512
#define K1E   (CH / K1T)           // 4 edges/thread
#define SRB   64                   // rows per K2 block (8 slices/bin)
#define CAPL  1536                 // LDS edge-list slots (mean 1023, +16 sigma)

// ===== K1: scores + f32->f16 convert + LDS-sorted bin partition + rel histogram =====
// Edge pack (u64): col:16 | rel:10 | rowlocal:9. 98 bins -> ~21-edge (168B) runs.
__global__ void __launch_bounds__(K1T)
k1_kernel(const int* __restrict__ rows, const int* __restrict__ cols,
          const int* __restrict__ rel, const float* __restrict__ dual,
          const float* __restrict__ conv_w, const float* __restrict__ conv_b,
          const float* __restrict__ inlayer, float* __restrict__ exp_scores,
          unsigned* __restrict__ relcnt, unsigned* __restrict__ bincur,
          unsigned long long* __restrict__ binbuf, __half2* __restrict__ hinl) {
    __shared__ unsigned long long sbuf[CH];     // 16 KB chunk staging (bin-sorted)
    __shared__ unsigned char sbin[CH];          // 2 KB per-slot bin id (98 < 256)
    __shared__ unsigned lcnt[NBIN], lstart[NBIN], lgb[NBIN];
    __shared__ unsigned lrel[N_REL];            // 4 KB relation histogram
    __shared__ unsigned w0sum;
    int t = threadIdx.x;
    int gtid = blockIdx.x * K1T + t;
    int lane = t & 63;

    // --- relation scores: one wave per relation (first 1000 waves of the grid) ---
    int wid = gtid >> 6;
    if (wid < N_REL) {
        const float* row = dual + (long)wid * D;
        float s = row[lane] * conv_w[lane] + row[lane + 64] * conv_w[lane + 64];
        #pragma unroll
        for (int off = 32; off > 0; off >>= 1) s += __shfl_down(s, off);
        if (lane == 0) {
            float v = s + conv_b[0];
            v = (v >= 0.f) ? v : 0.01f * v;        // leaky_relu
            exp_scores[wid] = expf(v);             // scores ~N(0,1): safe
        }
    }

    // --- f32 -> f16 convert (grid-stride float4, coalesced) ---
    const float4* src4 = (const float4*)inlayer;
    uint2* dst2 = (uint2*)hinl;
    for (int i = gtid; i < N_NODES * D / 4; i += NCH * K1T) {
        float4 f = src4[i];
        __half2 h0 = __floats2half2_rn(f.x, f.y);
        __half2 h1 = __floats2half2_rn(f.z, f.w);
        uint2 o; o.x = *(unsigned*)&h0; o.y = *(unsigned*)&h1;
        dst2[i] = o;
    }

    // --- partition this block's 2048-edge chunk ---
    if (t < NBIN) lcnt[t] = 0;
    for (int i = t; i < N_REL; i += K1T) lrel[i] = 0;
    __syncthreads();

    int n = NNZ - blockIdx.x * CH; if (n > CH) n = CH;   // tail = 1280 (mult of 4)
    int base4 = blockIdx.x * (CH / 4);

    int       ebin[K1E];
    unsigned  erank[K1E];
    unsigned long long epack[K1E];
    bool has = (4 * t < n);
    int4 rr, cc, qq;
    if (has) {
        rr = ((const int4*)rows)[base4 + t];
        cc = ((const int4*)cols)[base4 + t];
        qq = ((const int4*)rel)[base4 + t];
    }
    #pragma unroll
    for (int k = 0; k < K1E; ++k) {
        if (has) {
            int r = (k == 0) ? rr.x : (k == 1) ? rr.y : (k == 2) ? rr.z : rr.w;
            int c = (k == 0) ? cc.x : (k == 1) ? cc.y : (k == 2) ? cc.z : cc.w;
            int q = (k == 0) ? qq.x : (k == 1) ? qq.y : (k == 2) ? qq.z : qq.w;
            int b = r >> 9;
            epack[k] = (unsigned long long)(unsigned)c
                     | ((unsigned long long)(unsigned)q << 16)
                     | ((unsigned long long)(unsigned)(r & 511) << 26);
            ebin[k] = b;
            erank[k] = atomicAdd(&lcnt[b], 1u);
            atomicAdd(&lrel[q], 1u);
        } else ebin[k] = -1;
    }
    __syncthreads();

    // exclusive scan of 98 bin counts (2 waves) + reserve global runs
    unsigned v = (t < NBIN) ? lcnt[t] : 0u;
    if (t < 128) {
        #pragma unroll
        for (int off = 1; off < 64; off <<= 1) {
            unsigned y = __shfl_up(v, off);
            if (lane >= off) v += y;
        }
        if (t == 63) w0sum = v;
    }
    __syncthreads();
    if (t >= 64 && t < 128) v += w0sum;
    if (t < NBIN) {
        lstart[t] = v - lcnt[t];
        lgb[t] = atomicAdd(&bincur[t * 16], lcnt[t]);   // padded cursors: 1/line
    }
    // flush relation histogram (lrel stable since previous barrier)
    for (int i = t; i < N_REL; i += K1T) {
        unsigned cv = lrel[i];
        if (cv) atomicAdd(&relcnt[i], cv);
    }
    __syncthreads();

    // LDS scatter into bin-sorted order
    #pragma unroll
    for (int k = 0; k < K1E; ++k) {
        if (ebin[k] >= 0) {
            unsigned p = lstart[ebin[k]] + erank[k];
            sbuf[p] = epack[k];
            sbin[p] = (unsigned char)ebin[k];
        }
    }
    __syncthreads();

    // coalesced run writes: ~21-edge (168B) runs -> mostly full 64B lines
    #pragma unroll
    for (int k = 0; k < K1E; ++k) {
        int j = k * K1T + t;
        if (j < n) {
            int b = sbin[j];
            unsigned slot = lgb[b] + (unsigned)j - lstart[b];
            if (slot < CAP)
                binbuf[(unsigned long long)b * CAP + slot] = sbuf[j];
        }
    }
}

// ===== K2: fused place+gather — block = (bin, 64-row slice); LDS edge list =====
// Pass A: histogram owned rows. Pass B: row-sorted LDS compaction (L2-hot re-read).
// Gather: old TLP/MLP-rich quad engine, edges sourced from LDS. No bpack/starts.
__global__ void __launch_bounds__(512)
k2_kernel(const unsigned* __restrict__ bincur,
          const unsigned long long* __restrict__ binbuf,
          const float* __restrict__ exp_scores,
          const unsigned* __restrict__ relcnt,
          const __half2* __restrict__ hinl, float* __restrict__ out) {
    __shared__ unsigned list[CAPL];        // 6 KB row-sorted edge packs (col|rel<<16)
    __shared__ unsigned cnt[SRB], ex[SRB], cur[SRB];
    int t = threadIdx.x, lane = t & 63, w = t >> 6;
    int b   = blockIdx.x >> 3;             // bin 0..97
    int sub = blockIdx.x & 7;              // 64-row slice within bin

    if (t < SRB) cnt[t] = 0;

    // per-wave denom (global data only): denom = sum_r relcnt[r] * exp_scores[r]
    float dsum = 0.f;
    for (int i = lane; i < N_REL; i += 64)
        dsum += (float)relcnt[i] * exp_scores[i];
    #pragma unroll
    for (int off = 32; off > 0; off >>= 1) dsum += __shfl_down(dsum, off);
    float inv = 1.0f / __shfl(dsum, 0);

    __syncthreads();                       // cnt zeroed

    unsigned nb = bincur[b * 16]; if (nb > CAP) nb = CAP;
    const unsigned long long* bb = binbuf + (unsigned long long)b * CAP;

    // pass A: histogram owned rows (strided, coalesced)
    for (unsigned e = t; e < nb; e += 512u) {
        unsigned u = (unsigned)(bb[e] >> 26) & 511u;
        if ((u >> 6) == (unsigned)sub) atomicAdd(&cnt[u & 63u], 1u);
    }
    __syncthreads();

    // wave 0: exclusive scan of 64 row counts
    if (t < 64) {
        unsigned c0 = cnt[t];
        unsigned v = c0;
        #pragma unroll
        for (int off = 1; off < 64; off <<= 1) {
            unsigned y = __shfl_up(v, off);
            if (lane >= off) v += y;
        }
        ex[t] = v - c0;
        cur[t] = v - c0;
    }
    __syncthreads();

    // pass B (L2-hot re-read): compact owned edges row-sorted into LDS
    for (unsigned e = t; e < nb; e += 512u) {
        unsigned long long pk = bb[e];
        unsigned u = (unsigned)(pk >> 26) & 511u;
        if ((u >> 6) == (unsigned)sub) {
            unsigned idx = atomicAdd(&cur[u & 63u], 1u);
            if (idx < CAPL) list[idx] = (unsigned)pk & 0x3FFFFFFu;
        }
    }
    __syncthreads();

    // gather: wave w owns rows w*8 .. w*8+7; quad engine (4 rows/load in flight)
    int quad = lane >> 4;                  // which of 4 rows per load
    int l16  = lane & 15;                  // 8-dim group within row
    for (int i = 0; i < 8; ++i) {
        int rl = w * 8 + i;
        int node = b * RB + sub * SRB + rl;
        int s0 = (int)ex[rl];
        int e0 = s0 + (int)cnt[rl];
        if (e0 > CAPL) e0 = CAPL;          // statistically unreachable guard
        float a0=0.f,a1=0.f,a2=0.f,a3=0.f,a4=0.f,a5=0.f,a6=0.f,a7=0.f;
        for (int base = s0; base < e0; base += 64) {
            int rem = e0 - base; if (rem > 64) rem = 64;
            int px = 0, py = 0;
            if (lane < rem) {
                unsigned pk = list[base + lane];            // LDS, conflict-free
                px = (int)(pk & 0xFFFFu);
                py = __float_as_int(exp_scores[pk >> 16]);  // 4KB: L1-resident
            }
            for (int j = 0; j < rem; j += 16) {
                #pragma unroll
                for (int k = 0; k < 16; k += 4) {
                    if (j + k < rem) {     // wave-uniform guard
                        int idx = j + k + quad;
                        int   c = __shfl(px, idx);          // 0 beyond rem -> wv*0
                        float wv = __int_as_float(__shfl(py, idx));
                        const __half2* hp = hinl + (long)c * (D / 2) + l16 * 4;
                        uint4 hv = *(const uint4*)hp;       // 8 halves (16B)
                        float2 f0 = __half22float2(*(const __half2*)&hv.x);
                        float2 f1 = __half22float2(*(const __half2*)&hv.y);
                        float2 f2 = __half22float2(*(const __half2*)&hv.z);
                        float2 f3 = __half22float2(*(const __half2*)&hv.w);
                        a0 += wv * f0.x; a1 += wv * f0.y;
                        a2 += wv * f1.x; a3 += wv * f1.y;
                        a4 += wv * f2.x; a5 += wv * f2.y;
                        a6 += wv * f3.x; a7 += wv * f3.y;
                    }
                }
            }
        }
        #define COMB(x) x += __shfl(x, lane ^ 16); x += __shfl(x, lane ^ 32);
        COMB(a0) COMB(a1) COMB(a2) COMB(a3) COMB(a4) COMB(a5) COMB(a6) COMB(a7)
        #undef COMB
        if (lane < 32 && node < N_NODES) { // 32 lanes cover the 512B row store
            float4 v;
            int hi = (lane >> 4) & 1;      // 0: dims 0-3 of group, 1: dims 4-7
            if (hi) { v.x = a4*inv; v.y = a5*inv; v.z = a6*inv; v.w = a7*inv; }
            else    { v.x = a0*inv; v.y = a1*inv; v.z = a2*inv; v.w = a3*inv; }
            *(float4*)(out + (long)node * D + l16 * 8 + hi * 4) = v;
        }
    }
}

extern "C" void kernel_launch(void* const* d_in, const int* in_sizes, int n_in,
                              void* d_out, int out_size, void* d_ws, size_t ws_size,
                              hipStream_t stream) {
    const float* inlayer  = (const float*)d_in[0];
    const float* dual     = (const float*)d_in[1];
    const float* conv_w   = (const float*)d_in[2];
    const float* conv_b   = (const float*)d_in[3];
    const int*   edge_idx = (const int*)d_in[4];   // [2, NNZ]: rows then cols
    const int*   edge_rel = (const int*)d_in[5];
    float* out = (float*)d_out;
    const int* rows = edge_idx;
    const int* cols = edge_idx + NNZ;

    // workspace layout (16B aligned) — total ~20.9 MB
    char* ws = (char*)d_ws;
    float*              exp_scores = (float*)             (ws);             // 4 KB
    unsigned*           relcnt     = (unsigned*)          (ws + 4096);      // 4 KB (memset)
    unsigned*           bincur     = (unsigned*)          (ws + 8192);      // 98*64B (memset)
    unsigned long long* binbuf     = (unsigned long long*)(ws + 16384);     // 98*10240*8 = 8.03 MB
    __half2*            hinl       = (__half2*)           (ws + 16384 + 8028160); // 12.8 MB

    // zero relcnt + bincur in one 12 KB fill
    hipMemsetAsync(ws + 4096, 0, 12288, stream);

    k1_kernel<<<NCH, K1T, 0, stream>>>(rows, cols, edge_rel, dual, conv_w, conv_b,
                                       inlayer, exp_scores, relcnt, bincur,
                                       binbuf, hinl);
    k2_kernel<<<NBIN * 8, 512, 0, stream>>>(bincur, binbuf, exp_scores, relcnt,
                                            hinl, out);
}

// Round 11
// 140.565 us; speedup vs baseline: 5.8956x; 1.0496x over previous
//
#include <hip/hip_runtime.h>
#include <hip/hip_fp16.h>
#include <math.h>

#define N_NODES 50000
#define N_REL   1000
#define D       128
#define NNZ     800000

#define RB    512                  // rows per k1 bin (full-line write runs)
#define NBIN  98                   // ceil(50000/512)
#define CAP   10240                // slots/bin: mean 8184, sigma ~90
#define CH    2048                 // edges per partition chunk
#define NCH   ((NNZ + CH - 1) / CH)   // 391 chunks/blocks
#define K1T   512
#define K1E   (CH / K1T)           // 4 edges/thread
#define SRB   64                   // rows per K2 block (8 slices/bin)
#define CAPL  1536                 // LDS edge-list slots (mean 1023, +16 sigma)

// ===== K1: scores + f32->f16 convert + LDS-sorted bin partition + rel histogram =====
// Edge pack (u64): col:16 | rel:10 | rowlocal:9. 98 bins -> ~21-edge (168B) runs.
__global__ void __launch_bounds__(K1T)
k1_kernel(const int* __restrict__ rows, const int* __restrict__ cols,
          const int* __restrict__ rel, const float* __restrict__ dual,
          const float* __restrict__ conv_w, const float* __restrict__ conv_b,
          const float* __restrict__ inlayer, float* __restrict__ exp_scores,
          unsigned* __restrict__ relcnt, unsigned* __restrict__ bincur,
          unsigned long long* __restrict__ binbuf, __half2* __restrict__ hinl) {
    __shared__ unsigned long long sbuf[CH];     // 16 KB chunk staging (bin-sorted)
    __shared__ unsigned char sbin[CH];          // 2 KB per-slot bin id (98 < 256)
    __shared__ unsigned lcnt[NBIN], lstart[NBIN], lgb[NBIN];
    __shared__ unsigned lrel[N_REL];            // 4 KB relation histogram
    __shared__ unsigned w0sum;
    int t = threadIdx.x;
    int gtid = blockIdx.x * K1T + t;
    int lane = t & 63;

    // --- relation scores: one wave per relation (first 1000 waves of the grid) ---
    int wid = gtid >> 6;
    if (wid < N_REL) {
        const float* row = dual + (long)wid * D;
        float s = row[lane] * conv_w[lane] + row[lane + 64] * conv_w[lane + 64];
        #pragma unroll
        for (int off = 32; off > 0; off >>= 1) s += __shfl_down(s, off);
        if (lane == 0) {
            float v = s + conv_b[0];
            v = (v >= 0.f) ? v : 0.01f * v;        // leaky_relu
            exp_scores[wid] = expf(v);             // scores ~N(0,1): safe
        }
    }

    // --- f32 -> f16 convert (grid-stride float4, coalesced) ---
    const float4* src4 = (const float4*)inlayer;
    uint2* dst2 = (uint2*)hinl;
    for (int i = gtid; i < N_NODES * D / 4; i += NCH * K1T) {
        float4 f = src4[i];
        __half2 h0 = __floats2half2_rn(f.x, f.y);
        __half2 h1 = __floats2half2_rn(f.z, f.w);
        uint2 o; o.x = *(unsigned*)&h0; o.y = *(unsigned*)&h1;
        dst2[i] = o;
    }

    // --- partition this block's 2048-edge chunk ---
    if (t < NBIN) lcnt[t] = 0;
    for (int i = t; i < N_REL; i += K1T) lrel[i] = 0;
    __syncthreads();

    int n = NNZ - blockIdx.x * CH; if (n > CH) n = CH;   // tail = 1280 (mult of 4)
    int base4 = blockIdx.x * (CH / 4);

    int       ebin[K1E];
    unsigned  erank[K1E];
    unsigned long long epack[K1E];
    bool has = (4 * t < n);
    int4 rr, cc, qq;
    if (has) {
        rr = ((const int4*)rows)[base4 + t];
        cc = ((const int4*)cols)[base4 + t];
        qq = ((const int4*)rel)[base4 + t];
    }
    #pragma unroll
    for (int k = 0; k < K1E; ++k) {
        if (has) {
            int r = (k == 0) ? rr.x : (k == 1) ? rr.y : (k == 2) ? rr.z : rr.w;
            int c = (k == 0) ? cc.x : (k == 1) ? cc.y : (k == 2) ? cc.z : cc.w;
            int q = (k == 0) ? qq.x : (k == 1) ? qq.y : (k == 2) ? qq.z : qq.w;
            int b = r >> 9;
            epack[k] = (unsigned long long)(unsigned)c
                     | ((unsigned long long)(unsigned)q << 16)
                     | ((unsigned long long)(unsigned)(r & 511) << 26);
            ebin[k] = b;
            erank[k] = atomicAdd(&lcnt[b], 1u);
            atomicAdd(&lrel[q], 1u);
        } else ebin[k] = -1;
    }
    __syncthreads();

    // exclusive scan of 98 bin counts (2 waves) + reserve global runs
    unsigned v = (t < NBIN) ? lcnt[t] : 0u;
    if (t < 128) {
        #pragma unroll
        for (int off = 1; off < 64; off <<= 1) {
            unsigned y = __shfl_up(v, off);
            if (lane >= off) v += y;
        }
        if (t == 63) w0sum = v;
    }
    __syncthreads();
    if (t >= 64 && t < 128) v += w0sum;
    if (t < NBIN) {
        lstart[t] = v - lcnt[t];
        lgb[t] = atomicAdd(&bincur[t * 16], lcnt[t]);   // padded cursors: 1/line
    }
    // flush relation histogram (lrel stable since previous barrier)
    for (int i = t; i < N_REL; i += K1T) {
        unsigned cv = lrel[i];
        if (cv) atomicAdd(&relcnt[i], cv);
    }
    __syncthreads();

    // LDS scatter into bin-sorted order
    #pragma unroll
    for (int k = 0; k < K1E; ++k) {
        if (ebin[k] >= 0) {
            unsigned p = lstart[ebin[k]] + erank[k];
            sbuf[p] = epack[k];
            sbin[p] = (unsigned char)ebin[k];
        }
    }
    __syncthreads();

    // coalesced run writes: ~21-edge (168B) runs -> mostly full 64B lines
    #pragma unroll
    for (int k = 0; k < K1E; ++k) {
        int j = k * K1T + t;
        if (j < n) {
            int b = sbin[j];
            unsigned slot = lgb[b] + (unsigned)j - lstart[b];
            if (slot < CAP)
                binbuf[(unsigned long long)b * CAP + slot] = sbuf[j];
        }
    }
}

// ===== K2: fused place+gather — XCD-pinned (bin, slice) blocks; 1 global pass =====
// Single binbuf read per slice (push unsorted to LDS + histogram in one pass,
// then LDS->LDS row-sort). All 8 slices of a bin share wgid%8 -> same XCD L2.
__global__ void __launch_bounds__(512)
k2_kernel(const unsigned* __restrict__ bincur,
          const unsigned long long* __restrict__ binbuf,
          const float* __restrict__ exp_scores,
          const unsigned* __restrict__ relcnt,
          const __half2* __restrict__ hinl, float* __restrict__ out) {
    __shared__ unsigned ulist[CAPL];       // 6 KB unsorted owned edges
    __shared__ unsigned list[CAPL];        // 6 KB row-sorted (col|rel<<16)
    __shared__ unsigned cnt[SRB], ex[SRB], cur[SRB];
    __shared__ unsigned total;
    int t = threadIdx.x, lane = t & 63, w = t >> 6;
    // XCD-pinned decode: wgid%8 == bin%8 for all 8 slices of a bin (grid=832)
    int x = blockIdx.x & 7;
    int j = blockIdx.x >> 3;               // 0..103
    int b = x + 8 * (j >> 3);              // bin
    int sub = j & 7;                       // 64-row slice within bin
    if (b >= NBIN) return;                 // 48 pad blocks exit (uniform per block)

    if (t < SRB) cnt[t] = 0;
    if (t == 0) total = 0;

    // per-wave denom (global data only): denom = sum_r relcnt[r] * exp_scores[r]
    float dsum = 0.f;
    for (int i = lane; i < N_REL; i += 64)
        dsum += (float)relcnt[i] * exp_scores[i];
    #pragma unroll
    for (int off = 32; off > 0; off >>= 1) dsum += __shfl_down(dsum, off);
    float inv = 1.0f / __shfl(dsum, 0);

    __syncthreads();                       // cnt/total zeroed

    unsigned nb = bincur[b * 16]; if (nb > CAP) nb = CAP;
    const unsigned long long* bb = binbuf + (unsigned long long)b * CAP;

    // single global pass: filter own slice, push unsorted + histogram
    for (unsigned e = t; e < nb; e += 512u) {
        unsigned long long pk = bb[e];     // coalesced; slice-mates hit XCD L2
        unsigned u = (unsigned)(pk >> 26) & 511u;
        if ((u >> 6) == (unsigned)sub) {
            unsigned lo = (unsigned)pk;    // col:16|rel:10|row6 in bits 26..31
            unsigned idx = atomicAdd(&total, 1u);
            if (idx < CAPL) ulist[idx] = lo;
            atomicAdd(&cnt[lo >> 26], 1u);
        }
    }
    __syncthreads();

    // wave 0: exclusive scan of 64 row counts
    if (t < 64) {
        unsigned c0 = cnt[t];
        unsigned v = c0;
        #pragma unroll
        for (int off = 1; off < 64; off <<= 1) {
            unsigned y = __shfl_up(v, off);
            if (lane >= off) v += y;
        }
        ex[t] = v - c0;
        cur[t] = v - c0;
    }
    __syncthreads();

    // LDS -> LDS row-sorted scatter
    unsigned tot = total; if (tot > CAPL) tot = CAPL;
    for (unsigned i = t; i < tot; i += 512u) {
        unsigned lo = ulist[i];
        unsigned idx = atomicAdd(&cur[lo >> 26], 1u);
        if (idx < CAPL) list[idx] = lo & 0x3FFFFFFu;
    }
    __syncthreads();

    // gather: wave w owns rows w*8 .. w*8+7; quad engine (4 rows/load in flight)
    int quad = lane >> 4;                  // which of 4 rows per load
    int l16  = lane & 15;                  // 8-dim group within row
    for (int i = 0; i < 8; ++i) {
        int rl = w * 8 + i;
        int node = b * RB + sub * SRB + rl;
        int s0 = (int)ex[rl];
        int e0 = s0 + (int)cnt[rl];
        if (e0 > CAPL) e0 = CAPL;          // statistically unreachable guard
        float a0=0.f,a1=0.f,a2=0.f,a3=0.f,a4=0.f,a5=0.f,a6=0.f,a7=0.f;
        for (int base = s0; base < e0; base += 64) {
            int rem = e0 - base; if (rem > 64) rem = 64;
            int px = 0, py = 0;
            if (lane < rem) {
                unsigned pk = list[base + lane];            // LDS, conflict-free
                px = (int)(pk & 0xFFFFu);
                py = __float_as_int(exp_scores[pk >> 16]);  // 4KB: L1-resident
            }
            for (int jj = 0; jj < rem; jj += 16) {
                #pragma unroll
                for (int k = 0; k < 16; k += 4) {
                    if (jj + k < rem) {    // wave-uniform guard
                        int idx = jj + k + quad;
                        int   c = __shfl(px, idx);          // 0 beyond rem -> wv*0
                        float wv = __int_as_float(__shfl(py, idx));
                        const __half2* hp = hinl + (long)c * (D / 2) + l16 * 4;
                        uint4 hv = *(const uint4*)hp;       // 8 halves (16B)
                        float2 f0 = __half22float2(*(const __half2*)&hv.x);
                        float2 f1 = __half22float2(*(const __half2*)&hv.y);
                        float2 f2 = __half22float2(*(const __half2*)&hv.z);
                        float2 f3 = __half22float2(*(const __half2*)&hv.w);
                        a0 += wv * f0.x; a1 += wv * f0.y;
                        a2 += wv * f1.x; a3 += wv * f1.y;
                        a4 += wv * f2.x; a5 += wv * f2.y;
                        a6 += wv * f3.x; a7 += wv * f3.y;
                    }
                }
            }
        }
        #define COMB(x) x += __shfl(x, lane ^ 16); x += __shfl(x, lane ^ 32);
        COMB(a0) COMB(a1) COMB(a2) COMB(a3) COMB(a4) COMB(a5) COMB(a6) COMB(a7)
        #undef COMB
        if (lane < 32 && node < N_NODES) { // 32 lanes cover the 512B row store
            float4 v;
            int hi = (lane >> 4) & 1;      // 0: dims 0-3 of group, 1: dims 4-7
            if (hi) { v.x = a4*inv; v.y = a5*inv; v.z = a6*inv; v.w = a7*inv; }
            else    { v.x = a0*inv; v.y = a1*inv; v.z = a2*inv; v.w = a3*inv; }
            *(float4*)(out + (long)node * D + l16 * 8 + hi * 4) = v;
        }
    }
}

extern "C" void kernel_launch(void* const* d_in, const int* in_sizes, int n_in,
                              void* d_out, int out_size, void* d_ws, size_t ws_size,
                              hipStream_t stream) {
    const float* inlayer  = (const float*)d_in[0];
    const float* dual     = (const float*)d_in[1];
    const float* conv_w   = (const float*)d_in[2];
    const float* conv_b   = (const float*)d_in[3];
    const int*   edge_idx = (const int*)d_in[4];   // [2, NNZ]: rows then cols
    const int*   edge_rel = (const int*)d_in[5];
    float* out = (float*)d_out;
    const int* rows = edge_idx;
    const int* cols = edge_idx + NNZ;

    // workspace layout (16B aligned) — total ~20.9 MB
    char* ws = (char*)d_ws;
    float*              exp_scores = (float*)             (ws);             // 4 KB
    unsigned*           relcnt     = (unsigned*)          (ws + 4096);      // 4 KB (memset)
    unsigned*           bincur     = (unsigned*)          (ws + 8192);      // 98*64B (memset)
    unsigned long long* binbuf     = (unsigned long long*)(ws + 16384);     // 98*10240*8 = 8.03 MB
    __half2*            hinl       = (__half2*)           (ws + 16384 + 8028160); // 12.8 MB

    // zero relcnt + bincur in one 12 KB fill
    hipMemsetAsync(ws + 4096, 0, 12288, stream);

    k1_kernel<<<NCH, K1T, 0, stream>>>(rows, cols, edge_rel, dual, conv_w, conv_b,
                                       inlayer, exp_scores, relcnt, bincur,
                                       binbuf, hinl);
    k2_kernel<<<104 * 8, 512, 0, stream>>>(bincur, binbuf, exp_scores, relcnt,
                                           hinl, out);
}